// Round 1
// 155.352 us; speedup vs baseline: 1.0210x; 1.0210x over previous
//
#include <hip/hip_runtime.h>
#include <hip/hip_bf16.h>
#include <stdint.h>

#define B_   2
#define C_   256
#define P_   4096   // H*W = 64*64
#define N_   8
#define OUTC 2592   // N_ * 324

typedef __bf16 bf16x8 __attribute__((ext_vector_type(8)));
typedef float floatx4 __attribute__((ext_vector_type(4)));
typedef unsigned short ushort8 __attribute__((ext_vector_type(8)));

__device__ __forceinline__ float bf2f(unsigned int u16) {
    union { unsigned int i; float f; } x; x.i = u16 << 16; return x.f;
}
__device__ __forceinline__ unsigned int f2bf(float f) {
    union { float f; unsigned int i; } x; x.f = f;
    unsigned int u = x.i + 0x7FFFu + ((x.i >> 16) & 1u);  // RNE
    return u >> 16;
}

// ---------------- fmaps (B,C,P) fp32 -> (B,P,C) bf16, both in one dispatch ----------------
__global__ void conv_both(const float* __restrict__ in1, const float* __restrict__ in2,
                          __hip_bfloat16* __restrict__ out1, __hip_bfloat16* __restrict__ out2) {
    __shared__ float tile[32][33];
    int which = blockIdx.z >> 1;
    int b  = blockIdx.z & 1;
    const float* in = which ? in2 : in1;
    __hip_bfloat16* out = which ? out2 : out1;
    int p0 = blockIdx.x * 32;
    int c0 = blockIdx.y * 32;
    int tx = threadIdx.x;   // 0..31
    int ty0 = threadIdx.y;  // 0..7
    const float* ip = in + ((size_t)b * C_ + c0) * P_ + p0;
    for (int r = 0; r < 4; r++) {
        int ty = ty0 + r * 8;
        tile[ty][tx] = ip[(size_t)ty * P_ + tx];
    }
    __syncthreads();
    __hip_bfloat16* op = out + ((size_t)b * P_ + p0) * C_ + c0;
    for (int r = 0; r < 4; r++) {
        int ty = ty0 + r * 8;
        op[(size_t)ty * C_ + tx] = __float2bfloat16(tile[tx][ty]);
    }
}

// ---------------- corr GEMM: corr[p][q] = A[p]·B[q]/16, bf16 out ------
// Epilogue: per-wave LDS transpose (reusing the dead staging buffer) so the
// C-write is 8x global_store_dwordx4 per thread instead of 64 scalar u16 stores.
__global__ __launch_bounds__(256) void gemm_corr(const __hip_bfloat16* __restrict__ A,
                                                 const __hip_bfloat16* __restrict__ Bm,
                                                 unsigned short* __restrict__ Cmat) {
    __shared__ __align__(16) __hip_bfloat16 lsmem[8192];  // lA = [0,4096), lB = [4096,8192)
    __hip_bfloat16* lA = lsmem;
    __hip_bfloat16* lB = lsmem + 4096;
    const int id = blockIdx.x;           // 0..2047
    const int bz = id >> 10;
    const int r_ = id & 1023;
    const int s_ = r_ >> 3;
    const int by = (r_ & 7) * 4 + (s_ >> 5);
    const int bx = s_ & 31;
    const int m0 = by * 128;
    const int n0 = bx * 128;
    const __hip_bfloat16* Ab = A  + (size_t)bz * P_ * C_;
    const __hip_bfloat16* Bb = Bm + (size_t)bz * P_ * C_;
    unsigned short* Cb = Cmat + (size_t)bz * P_ * P_;

    const int tid  = threadIdx.x;
    const int lane = tid & 63;
    const int w    = tid >> 6;       // 0..3
    const int wm   = w & 1, wn = w >> 1;

    floatx4 acc[4][4];
    for (int i = 0; i < 4; i++)
        for (int j = 0; j < 4; j++)
            acc[i][j] = floatx4{0.f, 0.f, 0.f, 0.f};

    const int srow = w * 16 + (lane >> 2);
    const int scol = (lane & 3) * 8;

    for (int k0 = 0; k0 < C_; k0 += 32) {
        for (int j = 0; j < 2; j++) {
            int row = j * 64 + srow;
            const __hip_bfloat16* ga = Ab + (size_t)(m0 + row) * C_ + k0 + scol;
            const __hip_bfloat16* gb = Bb + (size_t)(n0 + row) * C_ + k0 + scol;
            __hip_bfloat16* la = lA + (j * 64 + w * 16) * 32;
            __hip_bfloat16* lb = lB + (j * 64 + w * 16) * 32;
            __builtin_amdgcn_global_load_lds((const __attribute__((address_space(1))) void*)ga,
                                             (__attribute__((address_space(3))) void*)la, 16, 0, 0);
            __builtin_amdgcn_global_load_lds((const __attribute__((address_space(1))) void*)gb,
                                             (__attribute__((address_space(3))) void*)lb, 16, 0, 0);
        }
        __syncthreads();
        const int kq   = (lane >> 4) * 8;
        const int rsel = lane & 15;
        bf16x8 af[4], bfv[4];
        for (int i = 0; i < 4; i++) {
            af[i]  = *(const bf16x8*)&lA[(wm * 64 + i * 16 + rsel) * 32 + kq];
            bfv[i] = *(const bf16x8*)&lB[(wn * 64 + i * 16 + rsel) * 32 + kq];
        }
        for (int i = 0; i < 4; i++)
            for (int j = 0; j < 4; j++)
                acc[i][j] = __builtin_amdgcn_mfma_f32_16x16x32_bf16(af[i], bfv[j], acc[i][j], 0, 0, 0);
        __syncthreads();
    }
    // After the loop's final barrier every wave is done reading lA/lB; each wave
    // now uses a PRIVATE 16x72-short scratch (1152 shorts, 4*1152 <= 8192) —
    // no further barriers needed (in-wave DS ordering + compiler lgkmcnt).
    const float scale = 0.0625f;  // 1/sqrt(256)
    unsigned short* sc = (unsigned short*)lsmem + w * (16 * 72);
    const int r16   = (lane >> 4) * 4;   // C/D frag: row=(lane>>4)*4+r, col=lane&15
    const int cbase = lane & 15;
    const int rdrow = lane >> 3;         // 0..7
    const int rdcol = (lane & 7) * 8;    // 0..56
    for (int i = 0; i < 4; i++) {        // 16-row chunk of this wave's 64x64 quadrant
        #pragma unroll
        for (int j = 0; j < 4; j++)
            #pragma unroll
            for (int r = 0; r < 4; r++)
                sc[(r16 + r) * 72 + cbase + j * 16] = (unsigned short)f2bf(acc[i][j][r] * scale);
        // row stride 144 B (16B-aligned): b128 row reads are LDS-BW-floor-bound
        ushort8 v0 = *(const ushort8*)&sc[rdrow * 72 + rdcol];
        ushort8 v1 = *(const ushort8*)&sc[(rdrow + 8) * 72 + rdcol];
        const int grow = m0 + wm * 64 + i * 16;
        const int gcol = n0 + wn * 64 + rdcol;
        *(ushort8*)&Cb[(size_t)(grow + rdrow) * P_ + gcol]     = v0;  // 8 rows x 128B lines/wave
        *(ushort8*)&Cb[(size_t)(grow + rdrow + 8) * P_ + gcol] = v1;
    }
}

// ---------------- pyramid + bilinear sampling fused, one block per (b,h,w) ----------------
// Stages the 64x64 bf16 level-0 row into padded LDS, pools levels 1-3 IN LDS,
// then samples. Main loop emits float4 stores (324 = 81*4 so each quad shares n).
__global__ __launch_bounds__(256) void sample_k(const unsigned short* __restrict__ c0,
                                                const float* __restrict__ coords,
                                                float* __restrict__ outp) {
    __shared__ unsigned short sl16[5680];  // 66*64 | 34*32 @4224 | 18*16 @5312 | 10*8 @5600
    __shared__ float cs[16];
    __shared__ float2 xt[288];             // {fx, bits: x0 | x1<<8}
    __shared__ float2 yt[288];             // {fy, bits: (base+y0*pw) | (base+y1*pw)<<16}
    __shared__ __align__(16) unsigned int ctb[324];  // (l*9+i9)<<8 | (l*9+j9)

    const int bp = blockIdx.x;     // b*4096 + p
    const int b  = bp >> 12;
    const int p  = bp & 4095;
    const int tid = threadIdx.x;
    unsigned int* slu = (unsigned int*)sl16;

    // ---- stage level-0 row (bf16, padded stride 66) + coords ----
    {
        const uint4* g0 = (const uint4*)(c0 + (size_t)bp * 4096);  // 512 x 16B
        for (int i = tid; i < 512; i += 256) {
            uint4 v = g0[i];
            int y = i >> 3, xh = (i & 7) * 4;     // uint col within row
            int u = y * 33 + xh;                  // short stride 66 = uint stride 33
            slu[u] = v.x; slu[u + 1] = v.y; slu[u + 2] = v.z; slu[u + 3] = v.w;
        }
        if (tid < 16) cs[tid] = coords[(size_t)(b * 16 + tid) * 4096 + p];
    }
    __syncthreads();

    // ---- pool level 1 (32x32) from level 0; build tables concurrently ----
    for (int t = tid; t < 1024; t += 256) {
        int y = t >> 5, x = t & 31;
        unsigned int a = slu[y * 66 + x];          // row 2y,   cols 2x,2x+1
        unsigned int c = slu[y * 66 + 33 + x];     // row 2y+1, cols 2x,2x+1
        float s = 0.25f * (bf2f(a & 0xffff) + bf2f(a >> 16)
                         + bf2f(c & 0xffff) + bf2f(c >> 16));
        sl16[4224 + y * 34 + x] = (unsigned short)f2bf(s);
    }
    for (int t = tid; t < 324; t += 256) {
        if (t < 288) {
            int n = t / 36, rem = t - n * 36;
            int l = rem / 9, dd = rem - l * 9;
            int wl = 64 >> l;
            int pw   = (l == 0) ? 66 : (l == 1) ? 34 : (l == 2) ? 18 : 10;
            int base = (l == 0) ? 0  : (l == 1) ? 4224 : (l == 2) ? 5312 : 5600;
            float inv = 1.0f / (float)(1 << l);
            float mx = (float)(wl - 1);
            float cx = cs[n * 2 + 0], cy = cs[n * 2 + 1];
            float xx = fminf(fmaxf(cx * inv + (float)(dd - 4), 0.0f), mx);
            float yy = fminf(fmaxf(cy * inv + (float)(dd - 4), 0.0f), mx);
            float x0f = floorf(xx), y0f = floorf(yy);
            int x0 = (int)x0f, y0 = (int)y0f;
            int x1 = min(x0 + 1, wl - 1), y1 = min(y0 + 1, wl - 1);
            unsigned int xb = (unsigned int)x0 | ((unsigned int)x1 << 8);
            unsigned int yb = (unsigned int)(base + y0 * pw)
                            | ((unsigned int)(base + y1 * pw) << 16);
            xt[t] = make_float2(xx - x0f, __uint_as_float(xb));
            yt[t] = make_float2(yy - y0f, __uint_as_float(yb));
        }
        int c = t;
        int l = c / 81, k = c - l * 81;
        int i9 = k / 9, j9 = k - i9 * 9;
        ctb[c] = ((unsigned int)(l * 9 + i9) << 8) | (unsigned int)(l * 9 + j9);
    }
    __syncthreads();

    // ---- pool level 2 (16x16) from level 1 ----
    if (tid < 256) {
        int y = tid >> 4, x = tid & 15;
        unsigned int a = slu[2112 + 34 * y + x];       // L1 row 2y
        unsigned int c = slu[2112 + 34 * y + 17 + x];  // L1 row 2y+1
        float s = 0.25f * (bf2f(a & 0xffff) + bf2f(a >> 16)
                         + bf2f(c & 0xffff) + bf2f(c >> 16));
        sl16[5312 + y * 18 + x] = (unsigned short)f2bf(s);
    }
    __syncthreads();

    // ---- pool level 3 (8x8) from level 2 ----
    if (tid < 64) {
        int y = tid >> 3, x = tid & 7;
        unsigned int a = slu[2656 + 18 * y + x];       // L2 row 2y
        unsigned int c = slu[2656 + 18 * y + 9 + x];   // L2 row 2y+1
        float s = 0.25f * (bf2f(a & 0xffff) + bf2f(a >> 16)
                         + bf2f(c & 0xffff) + bf2f(c >> 16));
        sl16[5600 + y * 10 + x] = (unsigned short)f2bf(s);
    }
    __syncthreads();

    // ---- main loop: 648 float4 outputs (2592 scalars); 4 consecutive c share n ----
    const size_t outbase = (size_t)b * ((size_t)N_ * P_ * 324) + (size_t)p * 324;
    for (int k = 0; k < 3; k++) {
        int iq = tid + k * 256;
        if (iq < 648) {
            int n = (iq * 6473) >> 19;     // exact floor(iq/81) for iq < 648
            int q = iq - n * 81;
            int cc0 = q * 4;
            const uint4 cv4 = *(const uint4*)&ctb[cc0];
            const int tb = n * 36;
            float vj[4];
            #pragma unroll
            for (int j = 0; j < 4; j++) {
                unsigned int cv = (j == 0) ? cv4.x : (j == 1) ? cv4.y : (j == 2) ? cv4.z : cv4.w;
                float2 xv = xt[tb + (cv >> 8)];
                float2 yv = yt[tb + (cv & 255)];
                unsigned int xb = __float_as_uint(xv.y);
                unsigned int yb = __float_as_uint(yv.y);
                int x0 = xb & 255, x1 = xb >> 8;
                int r0 = yb & 0xffff, r1 = yb >> 16;
                float fx = xv.x, fy = yv.x;
                float v00 = bf2f(sl16[r0 + x0]);
                float v01 = bf2f(sl16[r0 + x1]);
                float v10 = bf2f(sl16[r1 + x0]);
                float v11 = bf2f(sl16[r1 + x1]);
                float vx0 = v00 + fx * (v01 - v00);
                float vx1 = v10 + fx * (v11 - v10);
                vj[j] = vx0 + fy * (vx1 - vx0);
            }
            *(float4*)&outp[outbase + (size_t)n * (324 * 4096) + cc0] =
                make_float4(vj[0], vj[1], vj[2], vj[3]);
        }
    }
}

extern "C" void kernel_launch(void* const* d_in, const int* in_sizes, int n_in,
                              void* d_out, int out_size, void* d_ws, size_t ws_size,
                              hipStream_t stream) {
    const float* fmap1  = (const float*)d_in[0];
    const float* fmap2  = (const float*)d_in[1];
    const float* coords = (const float*)d_in[2];
    float* out = (float*)d_out;

    char* ws = (char*)d_ws;
    size_t off = 0;
    auto alloc = [&](size_t bytes) {
        void* ptr = ws + off;
        off += (bytes + 255) & ~(size_t)255;
        return ptr;
    };
    __hip_bfloat16* f1t = (__hip_bfloat16*)alloc((size_t)B_ * P_ * C_ * 2);
    __hip_bfloat16* f2t = (__hip_bfloat16*)alloc((size_t)B_ * P_ * C_ * 2);
    unsigned short* corr0 = (unsigned short*)alloc((size_t)B_ * P_ * 4096 * 2);

    conv_both<<<dim3(128, 8, 2 * B_), dim3(32, 8), 0, stream>>>(fmap1, fmap2, f1t, f2t);

    gemm_corr<<<dim3(2048), dim3(256), 0, stream>>>(f1t, f2t, corr0);

    sample_k<<<dim3(B_ * P_), dim3(256), 0, stream>>>(corr0, coords, out);
}